// Round 5
// baseline (2603.859 us; speedup 1.0000x reference)
//
#include <hip/hip_runtime.h>
#include <hip/hip_bf16.h>
#include <math.h>

#define HID   1024
#define IN_D  600
#define IN_DP 608      // 600 padded to multiple of 32
#define BATCH 2048
#define TSTEP 20
#define BT    (BATCH * TSTEP)   // 40960
#define G3    3072

typedef __attribute__((ext_vector_type(8))) short bf16x8;
typedef __attribute__((ext_vector_type(4))) float f32x4;

#define GLB(p) ((const __attribute__((address_space(1))) void*)(p))
#define LDS(p) ((__attribute__((address_space(3))) void*)(p))

__device__ __forceinline__ short f2bf(float f) {
    __hip_bfloat16 b = __float2bfloat16(f);
    return *(short*)&b;
}
__device__ __forceinline__ float bf2f(short s) {
    __hip_bfloat16 b = *(__hip_bfloat16*)&s;
    return __bfloat162float(b);
}

// ---------------------------------------------------------------------------
// Input projection: gx[m, n] = bf16( x_bf[m, :] . Wih[n, :] + b_ih[n] ),
// m = t*BATCH + b (x_bf pre-transposed), row-major epilogue, m97 structure.
// (unchanged — attribution isolation for the gru fusion)
// ---------------------------------------------------------------------------
__global__ __launch_bounds__(256) void gemm_input(const short* __restrict__ X,
                                                  const short* __restrict__ W,
                                                  const float* __restrict__ b_ih,
                                                  short* __restrict__ gx) {
    __shared__ short sA[128 * 32];
    __shared__ short sB[128 * 32];

    const int id    = blockIdx.x;
    const int xcd   = id & 7;
    const int local = id >> 3;          // 0..959
    const int nsub  = local % 3;
    const int mblk  = local / 3;        // 0..319
    const int m0 = mblk * 128;
    const int n0 = (xcd * 3 + nsub) * 128;

    const int tid  = threadIdx.x;
    const int wave = tid >> 6;
    const int lane = tid & 63;
    const int wm = (wave >> 1) * 64;
    const int wn = (wave & 1) * 64;

    const int srow = tid >> 2;
    const int scol = (tid & 3) * 8;
    const int fm = lane & 15;
    const int fq = lane >> 4;

    f32x4 acc[4][4] = {};

    for (int k0 = 0; k0 < IN_DP; k0 += 32) {
#pragma unroll
        for (int j = 0; j < 2; ++j) {
            const short* ga = X + (size_t)(m0 + j * 64 + srow) * IN_DP + k0 + scol;
            __builtin_amdgcn_global_load_lds(GLB(ga), LDS(sA + j * 2048 + wave * 512), 16, 0, 0);
            const short* gb = W + (size_t)(n0 + j * 64 + srow) * IN_DP + k0 + scol;
            __builtin_amdgcn_global_load_lds(GLB(gb), LDS(sB + j * 2048 + wave * 512), 16, 0, 0);
        }
        __syncthreads();

        bf16x8 af[4], bf[4];
#pragma unroll
        for (int mi = 0; mi < 4; ++mi)
            af[mi] = *(const bf16x8*)(sA + (wm + mi * 16 + fm) * 32 + fq * 8);
#pragma unroll
        for (int ni = 0; ni < 4; ++ni)
            bf[ni] = *(const bf16x8*)(sB + (wn + ni * 16 + fm) * 32 + fq * 8);
#pragma unroll
        for (int mi = 0; mi < 4; ++mi)
#pragma unroll
            for (int ni = 0; ni < 4; ++ni)
                acc[mi][ni] = __builtin_amdgcn_mfma_f32_16x16x32_bf16(af[mi], bf[ni], acc[mi][ni], 0, 0, 0);
        __syncthreads();
    }

#pragma unroll
    for (int ni = 0; ni < 4; ++ni) {
        int gn = n0 + wn + ni * 16 + fm;
        float bias = b_ih[gn];
#pragma unroll
        for (int mi = 0; mi < 4; ++mi) {
#pragma unroll
            for (int r = 0; r < 4; ++r) {
                int gm = m0 + wm + mi * 16 + fq * 4 + r;
                gx[(size_t)gm * G3 + gn] = f2bf(acc[mi][ni][r] + bias);
            }
        }
    }
}

// ---------------------------------------------------------------------------
// v8: ALL 20 recurrent steps fused into ONE persistent kernel.
// v7 post-mortem: per-step kernels cost ~28 us vs ~11 us modeled in-kernel
// work — the gap is launch gaps + pipeline ramp + tail drain + L2-cold
// restart, x20. Fusion removes 19 of each.
//  - grid 256 x 512thr, 160 KB LDS -> exactly 1 block/CU: co-residency is
//    structural (k=1 x 256CU). Inter-step sync: per-step arrival counters
//    cnt[t] (no reset -> no reset race), relaxed spin by thread 0,
//    __threadfence() on BOTH sides (release: drain+wbl2 pushes h to L3;
//    acquire: buffer_inv kills stale-L2 — the G16 cross-XCD hazard that
//    kernel boundaries used to handle).
//  - v7's counted-vmcnt pipeline kept verbatim; prologue split: Wr part of
//    chunks 0/1 issued BEFORE the spin (no h dependency -> latency hides
//    under the barrier wait), h part after the acquire fence.
//    vmcnt ladder (uniform for all t): ic0 vmcnt(7), ic1..14 vmcnt(10),
//    ic15 vmcnt(6), vmcnt(0) only at epilogue. Derivation in comments below.
// ---------------------------------------------------------------------------
__global__ __launch_bounds__(512) void gru_fused(short* hb0, short* hb1,
                                                 const short* __restrict__ Wr,
                                                 const short* __restrict__ gx,
                                                 const float* __restrict__ b_hh,
                                                 float* __restrict__ out,
                                                 unsigned* __restrict__ cnt) {
    __shared__ short LDSF[4 * 20480];   // 160 KB: buf b at b*20480 (sA@0, sB@8192)
                                        // sGX tail-overlay at [0 .. 24576)

    const int id   = blockIdx.x;
    const int xcd  = id & 7;
    const int rest = id >> 3;           // 0..31
    const int jsub = rest & 1;
    const int mblk = rest >> 1;         // 0..15
    const int j0 = (xcd * 2 + jsub) * 64;
    const int m0 = mblk * 128;
    const int hchunk = j0 >> 6;         // k-chunk holding h[:, j0..j0+63]

    const int tid  = threadIdx.x;
    const int wave = tid >> 6;          // 0..7
    const int lane = tid & 63;
    const int wm = (wave >> 2) * 64;    // m-group: 0 or 64
    const int jg = wave & 3;            // j-group: 16 j each
    const int fm = lane & 15;
    const int fq = lane >> 4;

    const int srow8 = lane >> 3;               // 0..7 (row within 8-row group)
    const int sxor  = ((lane & 7) ^ srow8) * 8; // inverse-swizzled col (shorts)

    const short* Wblk = Wr + (size_t)(j0 * 3) * HID;   // 192 rows, K=1024
    const int jj = jg * 16 + fm;        // block-local j (0..63)
    const int jlane = j0 + jj;
    const float bh_r = b_hh[jlane];
    const float bh_i = b_hh[HID + jlane];
    const float bh_n = b_hh[2 * HID + jlane];

#pragma unroll 1
    for (int t = 0; t < TSTEP; ++t) {
        const short* hin  = (t & 1) ? hb1 : hb0;
        short*       hout = (t & 1) ? hb0 : hb1;
        const short* gxt  = gx + (size_t)t * BATCH * G3;

        // 3 Wr loads / wave / chunk (24 rows of 192 per wave)
        auto stageW = [&](int kc, int bsel) {
            int k0 = kc * 64;
            short* base = LDSF + bsel * 20480;
#pragma unroll
            for (int i = 0; i < 3; ++i) {
                int row0 = wave * 24 + i * 8;
                const short* g = Wblk + (size_t)(row0 + srow8) * HID + k0 + sxor;
                __builtin_amdgcn_global_load_lds(GLB(g), LDS(base + 8192 + row0 * 64), 16, 0, 0);
            }
        };
        // 2 h loads / wave / chunk (16 rows of 128 per wave)
        auto stageH = [&](int kc, int bsel) {
            int k0 = kc * 64;
            short* base = LDSF + bsel * 20480;
#pragma unroll
            for (int i = 0; i < 2; ++i) {
                int row0 = wave * 16 + i * 8;
                const short* g = hin + (size_t)(m0 + row0 + srow8) * HID + k0 + sxor;
                __builtin_amdgcn_global_load_lds(GLB(g), LDS(base + row0 * 64), 16, 0, 0);
            }
        };
        auto stage = [&](int kc, int bsel) { stageH(kc, bsel); stageW(kc, bsel); };
        // sGX instr q (0..47): gate q>>4, rows (q&15)*8..+7, 64 swizzled cols
        auto sgx_load = [&](int q) {
            int g = q >> 4;
            int row0 = (q & 15) * 8;
            const short* src = gxt + (size_t)(m0 + row0 + srow8) * G3 + g * HID + j0 + sxor;
            __builtin_amdgcn_global_load_lds(GLB(src), LDS(LDSF + q * 512), 16, 0, 0);
        };

        // ---- inter-step boundary --------------------------------------
        // (previous iteration ended: threadfence (release) + syncthreads,
        //  so all waves' sGX/epilogue LDS reads are retired -> safe to
        //  overwrite buf0/buf1 sB with next step's Wr chunks.)
        stageW(0, 0);                      // fly during the spin (no h dep)
        stageW(1, 1);
        if (t > 0) {
            if (tid == 0) {
                __hip_atomic_fetch_add(&cnt[t], 1u, __ATOMIC_RELAXED,
                                       __HIP_MEMORY_SCOPE_AGENT);
                while (__hip_atomic_load(&cnt[t], __ATOMIC_RELAXED,
                                         __HIP_MEMORY_SCOPE_AGENT) < 256u)
                    __builtin_amdgcn_s_sleep(2);
            }
            __syncthreads();
            __threadfence();               // acquire: drains Wr loads (they
                                           // flew during spin) + buffer_inv
                                           // -> fresh h visible below
        }
        stageH(0, 0);
        stageH(1, 1);

        f32x4 acc[4][3] = {};    // [m-frag][gate]
        short hsnap[4][4];       // h[m-frag rows][this lane's j]

        // vmcnt ladder (per wave). t>0: Wr0/Wr1 drained by the fence ->
        // outstanding at ic0 wait: [h0(2) h1(2) st2(5)] = 9, retire h0 ->
        // vmcnt(7). t=0: [Wr0(3) Wr1(3) h0(2) h1(2) st2(5)] = 15, retire
        // through h0 = oldest 8 -> vmcnt(7). Same number both cases.
        // ic1: +st3 -> retire h1 -> vmcnt(10) = steady state thereafter.
        // ic14: [st14 st15 sgxA] = 15 -> vmcnt(10). ic15: +sgxB -> 11 ->
        // retire st15 -> vmcnt(6). Epilogue: vmcnt(0) drains sGX.
#pragma unroll
        for (int ic = 0; ic < 16; ++ic) {
            if (ic < 14) {
                stage(ic + 2, (ic + 2) & 3);
            } else if (ic == 14) {
#pragma unroll
                for (int i = 0; i < 5; ++i) sgx_load(wave * 5 + i);  // 40KB -> buf0
            } else {
                sgx_load(40 + wave);                  // 8KB -> buf1 head
            }
            if (ic == 0)       asm volatile("s_waitcnt vmcnt(7)"  : : : "memory");
            else if (ic < 15)  asm volatile("s_waitcnt vmcnt(10)" : : : "memory");
            else               asm volatile("s_waitcnt vmcnt(6)"  : : : "memory");
            __builtin_amdgcn_s_barrier();
            __builtin_amdgcn_sched_barrier(0);    // no reads hoist above publish

            short* buf = LDSF + (ic & 3) * 20480;

            if (ic == hchunk) {              // snapshot h[:, j0..j0+63]
#pragma unroll
                for (int mi = 0; mi < 4; ++mi)
#pragma unroll
                    for (int r = 0; r < 4; ++r) {
                        int mrow = wm + mi * 16 + fq * 4 + r;
                        hsnap[mi][r] = buf[mrow * 64 + (jj ^ ((mrow & 7) * 8))];
                    }
            }

#pragma unroll
            for (int kk = 0; kk < 2; ++kk) {
                bf16x8 af[4], bg[3];
                const int cbase = kk * 32 + fq * 8;
                const int csw = cbase ^ ((fm & 7) * 8);   // swizzled read col
#pragma unroll
                for (int mi = 0; mi < 4; ++mi)
                    af[mi] = *(const bf16x8*)(&buf[(wm + mi * 16 + fm) * 64 + csw]);
#pragma unroll
                for (int g = 0; g < 3; ++g)
                    bg[g] = *(const bf16x8*)(&buf[8192 + (jg * 48 + g * 16 + fm) * 64 + csw]);
                __builtin_amdgcn_s_setprio(1);
#pragma unroll
                for (int mi = 0; mi < 4; ++mi)
#pragma unroll
                    for (int g = 0; g < 3; ++g)
                        acc[mi][g] = __builtin_amdgcn_mfma_f32_16x16x32_bf16(af[mi], bg[g], acc[mi][g], 0, 0, 0);
                __builtin_amdgcn_s_setprio(0);
            }
        }

        // Drain sGX, publish within block, then epilogue: LDS/register-only
        // inputs; global STORES only.
        asm volatile("s_waitcnt vmcnt(0)" : : : "memory");
        __builtin_amdgcn_s_barrier();
        __builtin_amdgcn_sched_barrier(0);

        const short* sGX = LDSF;            // [0 .. 24576) shorts
#pragma unroll
        for (int mi = 0; mi < 4; ++mi) {
#pragma unroll
            for (int r = 0; r < 4; ++r) {
                int mloc = wm + mi * 16 + fq * 4 + r;
                int gm = m0 + mloc;
                int jsw = jj ^ ((mloc & 7) * 8);          // sGX swizzled col
                float xr = bf2f(sGX[        mloc * 64 + jsw]);
                float xi = bf2f(sGX[ 8192 + mloc * 64 + jsw]);
                float xn = bf2f(sGX[16384 + mloc * 64 + jsw]);

                float rg = 1.0f / (1.0f + __expf(-(xr + acc[mi][0][r] + bh_r)));
                float ig = 1.0f / (1.0f + __expf(-(xi + acc[mi][1][r] + bh_i)));
                float ng = tanhf(xn + rg * (acc[mi][2][r] + bh_n));

                float h  = bf2f(hsnap[mi][r]);
                float hy = ng + ig * (h - ng);
                size_t idx = (size_t)gm * HID + jlane;
                hout[idx] = f2bf(hy);
                if (t == TSTEP - 1) out[idx] = hy;
            }
        }

        if (t < TSTEP - 1) {
            __threadfence();    // release: drain h stores + wbl2 -> L3
            __syncthreads();    // whole block past epilogue (LDS reads done)
        }
    }
}

// x [b][t][600] fp32 -> x_bf [t*B + b][608] bf16 zero-padded (transpose)
__global__ __launch_bounds__(256) void cvt_x(const float* __restrict__ X, short* __restrict__ Xb) {
    int rd = blockIdx.x;             // dst row = t*BATCH + b
    int tt = rd >> 11;               // /2048
    int b  = rd & (BATCH - 1);
    const float* s = X + ((size_t)b * TSTEP + tt) * IN_D;
    short* d = Xb + (size_t)rd * IN_DP;
    for (int c = threadIdx.x; c < IN_DP; c += 256)
        d[c] = (c < IN_D) ? f2bf(s[c]) : (short)0;
}

// W_ih [3072,600] fp32 -> [3072,608] bf16 zero-padded
__global__ __launch_bounds__(256) void cvt_wih(const float* __restrict__ W, short* __restrict__ Wb) {
    int r = blockIdx.x;
    for (int c = threadIdx.x; c < IN_DP; c += 256) {
        float v = (c < IN_D) ? W[(size_t)r * IN_D + c] : 0.f;
        Wb[(size_t)r * IN_DP + c] = f2bf(v);
    }
}

// W_hh -> Wr gate-block-interleaved bf16: Wr[jb*48+g*16+ji] = Whh[g*1024+jb*16+ji]
__global__ __launch_bounds__(256) void cvt_whh(const float* __restrict__ W, short* __restrict__ Wr) {
    int n  = blockIdx.x;             // dst row 0..3071
    int jb = n / 48;
    int rem = n - jb * 48;
    int g  = rem >> 4;
    int ji = rem & 15;
    const float* s = W + (size_t)(g * HID + jb * 16 + ji) * HID;
    short* d = Wr + (size_t)n * HID;
    for (int c = threadIdx.x; c < HID; c += 256) d[c] = f2bf(s[c]);
}

extern "C" void kernel_launch(void* const* d_in, const int* in_sizes, int n_in,
                              void* d_out, int out_size, void* d_ws, size_t ws_size,
                              hipStream_t stream) {
    const float* x    = (const float*)d_in[0];  // [B, T, IN_D]
    const float* W_ih = (const float*)d_in[1];  // [3H, IN_D]
    const float* b_ih = (const float*)d_in[2];
    const float* W_hh = (const float*)d_in[3];  // [3H, HID]
    const float* b_hh = (const float*)d_in[4];
    float* out = (float*)d_out;                 // [B, HID]

    char* p = (char*)d_ws;
    short* gx     = (short*)p;  p += (size_t)BT * G3 * 2;       // 251.7 MB, [t][b][3H]
    short* x_bf   = (short*)p;  p += (size_t)BT * IN_DP * 2;    //  49.8 MB, [t][b][608]
    short* hb0    = (short*)p;  p += (size_t)BATCH * HID * 2;   //   4.2 MB
    short* hb1    = (short*)p;  p += (size_t)BATCH * HID * 2;   //   4.2 MB
    short* Wih_bf = (short*)p;  p += (size_t)G3 * IN_DP * 2;    //   3.7 MB
    short* Whh_r  = (short*)p;  p += (size_t)G3 * HID * 2;      //   6.3 MB
    unsigned* bar = (unsigned*)p; p += 256;                     // cnt[t] barrier
    // total ~320 MB

    cvt_wih<<<G3, 256, 0, stream>>>(W_ih, Wih_bf);
    cvt_whh<<<G3, 256, 0, stream>>>(W_hh, Whh_r);
    cvt_x<<<BT, 256, 0, stream>>>(x, x_bf);
    hipMemsetAsync(hb0, 0, (size_t)BATCH * HID * 2, stream);
    hipMemsetAsync(bar, 0, 256, stream);

    // One big input projection over all timesteps (M = 40960, 1D swizzled)
    gemm_input<<<7680, 256, 0, stream>>>(x_bf, Wih_bf, b_ih, gx);

    // All 20 recurrent steps in one persistent kernel (1 block/CU x 256)
    gru_fused<<<256, 512, 0, stream>>>(hb0, hb1, Whh_r, gx, b_hh, out, bar);
}

// Round 7
// 1298.704 us; speedup vs baseline: 2.0050x; 2.0050x over previous
//
#include <hip/hip_runtime.h>
#include <hip/hip_bf16.h>
#include <math.h>

#define HID   1024
#define IN_D  600
#define IN_DP 608      // 600 padded to multiple of 32
#define BATCH 2048
#define TSTEP 20
#define BT    (BATCH * TSTEP)   // 40960
#define G3    3072

typedef __attribute__((ext_vector_type(8))) short bf16x8;
typedef __attribute__((ext_vector_type(4))) float f32x4;

#define GLB(p) ((const __attribute__((address_space(1))) void*)(p))
#define LDS(p) ((__attribute__((address_space(3))) void*)(p))

__device__ __forceinline__ short f2bf(float f) {
    __hip_bfloat16 b = __float2bfloat16(f);
    return *(short*)&b;
}
__device__ __forceinline__ float bf2f(short s) {
    __hip_bfloat16 b = *(__hip_bfloat16*)&s;
    return __bfloat162float(b);
}

// ---------------------------------------------------------------------------
// Input projection: gx[m, n] = bf16( x_bf[m, :] . Wih[n, :] + b_ih[n] ),
// m = t*BATCH + b (x_bf pre-transposed), row-major epilogue, m97 structure.
// (unchanged — attribution isolation for the gru coherence fix)
// ---------------------------------------------------------------------------
__global__ __launch_bounds__(256) void gemm_input(const short* __restrict__ X,
                                                  const short* __restrict__ W,
                                                  const float* __restrict__ b_ih,
                                                  short* __restrict__ gx) {
    __shared__ short sA[128 * 32];
    __shared__ short sB[128 * 32];

    const int id    = blockIdx.x;
    const int xcd   = id & 7;
    const int local = id >> 3;          // 0..959
    const int nsub  = local % 3;
    const int mblk  = local / 3;        // 0..319
    const int m0 = mblk * 128;
    const int n0 = (xcd * 3 + nsub) * 128;

    const int tid  = threadIdx.x;
    const int wave = tid >> 6;
    const int lane = tid & 63;
    const int wm = (wave >> 1) * 64;
    const int wn = (wave & 1) * 64;

    const int srow = tid >> 2;
    const int scol = (tid & 3) * 8;
    const int fm = lane & 15;
    const int fq = lane >> 4;

    f32x4 acc[4][4] = {};

    for (int k0 = 0; k0 < IN_DP; k0 += 32) {
#pragma unroll
        for (int j = 0; j < 2; ++j) {
            const short* ga = X + (size_t)(m0 + j * 64 + srow) * IN_DP + k0 + scol;
            __builtin_amdgcn_global_load_lds(GLB(ga), LDS(sA + j * 2048 + wave * 512), 16, 0, 0);
            const short* gb = W + (size_t)(n0 + j * 64 + srow) * IN_DP + k0 + scol;
            __builtin_amdgcn_global_load_lds(GLB(gb), LDS(sB + j * 2048 + wave * 512), 16, 0, 0);
        }
        __syncthreads();

        bf16x8 af[4], bf[4];
#pragma unroll
        for (int mi = 0; mi < 4; ++mi)
            af[mi] = *(const bf16x8*)(sA + (wm + mi * 16 + fm) * 32 + fq * 8);
#pragma unroll
        for (int ni = 0; ni < 4; ++ni)
            bf[ni] = *(const bf16x8*)(sB + (wn + ni * 16 + fm) * 32 + fq * 8);
#pragma unroll
        for (int mi = 0; mi < 4; ++mi)
#pragma unroll
            for (int ni = 0; ni < 4; ++ni)
                acc[mi][ni] = __builtin_amdgcn_mfma_f32_16x16x32_bf16(af[mi], bf[ni], acc[mi][ni], 0, 0, 0);
        __syncthreads();
    }

#pragma unroll
    for (int ni = 0; ni < 4; ++ni) {
        int gn = n0 + wn + ni * 16 + fm;
        float bias = b_ih[gn];
#pragma unroll
        for (int mi = 0; mi < 4; ++mi) {
#pragma unroll
            for (int r = 0; r < 4; ++r) {
                int gm = m0 + wm + mi * 16 + fq * 4 + r;
                gx[(size_t)gm * G3 + gn] = f2bf(acc[mi][ni][r] + bias);
            }
        }
    }
}

// ---------------------------------------------------------------------------
// v10: persistent 20-step kernel, h-coherence at DEVICE scope (not system).
// v9 post-mortem: container died twice, no verdict. v8 proved the persistent
// spin structure on this harness; v9's delta was the coherence ops, and its
// sc0|sc1 (= SYSTEM scope, host-coherent) on h loads/stores forces the
// memory/host path — the one exotic thing v9 did. Cross-XCD visibility only
// needs DEVICE scope (SC1 alone): stores write through past the per-XCD L2
// to the IF$ (L3); loads served coherently from IF$. h (4.2 MB) stays
// L3-resident.
//  - h STORES: global_store_short ... sc1 (device-scope write-through).
//    Release = loop-end __syncthreads (pre-barrier vmcnt(0) waits the store
//    acks) before thread0's device-scope arrival add (m20 mechanism).
//  - h LOADS (stageH): global_load_lds aux=16 (SC1): device-coherent,
//    bypasses stale local L1/L2.
//  - NO threadfence anywhere -> Wr + gx stay L2-resident across all steps
//    (v8's buffer_inv storm was FETCH 1.06 GB / 2228 us).
// vmcnt ladder (re-derived, valid for t=0 and t>0): ic0 vmcnt(7),
// ic1..14 vmcnt(10), ic15 vmcnt(6), vmcnt(0) only at epilogue.
// Geometry/pipeline identical to v8/v9: 128m x 64j x 3 gates, BK=64,
// 4 x 40KB staging bufs, sGX tail-overlay, 512 thr, 256 blocks (1/CU).
// ---------------------------------------------------------------------------
__global__ __launch_bounds__(512) void gru_fused(short* hb0, short* hb1,
                                                 const short* __restrict__ Wr,
                                                 const short* __restrict__ gx,
                                                 const float* __restrict__ b_hh,
                                                 float* __restrict__ out,
                                                 unsigned* __restrict__ cnt) {
    __shared__ short LDSF[4 * 20480];   // 160 KB: buf b at b*20480 (sA@0, sB@8192)
                                        // sGX tail-overlay at [0 .. 24576)

    const int id   = blockIdx.x;
    const int xcd  = id & 7;
    const int rest = id >> 3;           // 0..31
    const int jsub = rest & 1;
    const int mblk = rest >> 1;         // 0..15
    const int j0 = (xcd * 2 + jsub) * 64;
    const int m0 = mblk * 128;
    const int hchunk = j0 >> 6;         // k-chunk holding h[:, j0..j0+63]

    const int tid  = threadIdx.x;
    const int wave = tid >> 6;          // 0..7
    const int lane = tid & 63;
    const int wm = (wave >> 2) * 64;    // m-group: 0 or 64
    const int jg = wave & 3;            // j-group: 16 j each
    const int fm = lane & 15;
    const int fq = lane >> 4;

    const int srow8 = lane >> 3;               // 0..7 (row within 8-row group)
    const int sxor  = ((lane & 7) ^ srow8) * 8; // inverse-swizzled col (shorts)

    const short* Wblk = Wr + (size_t)(j0 * 3) * HID;   // 192 rows, K=1024
    const int jj = jg * 16 + fm;        // block-local j (0..63)
    const int jlane = j0 + jj;
    const float bh_r = b_hh[jlane];
    const float bh_i = b_hh[HID + jlane];
    const float bh_n = b_hh[2 * HID + jlane];

#pragma unroll 1
    for (int t = 0; t < TSTEP; ++t) {
        const short* hin  = (t & 1) ? hb1 : hb0;
        short*       hout = (t & 1) ? hb0 : hb1;
        const short* gxt  = gx + (size_t)t * BATCH * G3;

        // 3 Wr loads / wave / chunk (24 rows of 192 per wave) — L2-cached
        auto stageW = [&](int kc, int bsel) {
            int k0 = kc * 64;
            short* base = LDSF + bsel * 20480;
#pragma unroll
            for (int i = 0; i < 3; ++i) {
                int row0 = wave * 24 + i * 8;
                const short* g = Wblk + (size_t)(row0 + srow8) * HID + k0 + sxor;
                __builtin_amdgcn_global_load_lds(GLB(g), LDS(base + 8192 + row0 * 64), 16, 0, 0);
            }
        };
        // 2 h loads / wave / chunk — aux=16 (SC1): device-scope coherent,
        // served from IF$ (h written by other XCDs last step).
        auto stageH = [&](int kc, int bsel) {
            int k0 = kc * 64;
            short* base = LDSF + bsel * 20480;
#pragma unroll
            for (int i = 0; i < 2; ++i) {
                int row0 = wave * 16 + i * 8;
                const short* g = hin + (size_t)(m0 + row0 + srow8) * HID + k0 + sxor;
                __builtin_amdgcn_global_load_lds(GLB(g), LDS(base + row0 * 64), 16, 0, 16);
            }
        };
        auto stage = [&](int kc, int bsel) { stageH(kc, bsel); stageW(kc, bsel); };
        // sGX instr q (0..47): gate q>>4, rows (q&15)*8..+7, 64 swizzled cols
        auto sgx_load = [&](int q) {
            int g = q >> 4;
            int row0 = (q & 15) * 8;
            const short* src = gxt + (size_t)(m0 + row0 + srow8) * G3 + g * HID + j0 + sxor;
            __builtin_amdgcn_global_load_lds(GLB(src), LDS(LDSF + q * 512), 16, 0, 0);
        };

        // ---- inter-step boundary --------------------------------------
        // Previous iteration ended with __syncthreads(): all waves' sc1
        // h-stores are ACKED at the coherence point (pre-barrier vmcnt(0))
        // and all epilogue LDS reads retired -> safe to overwrite buf0/buf1
        // sB and to signal arrival.
        stageW(0, 0);                      // fly during the spin (no h dep)
        stageW(1, 1);
        if (t > 0) {
            if (tid == 0) {
                __hip_atomic_fetch_add(&cnt[t], 1u, __ATOMIC_RELAXED,
                                       __HIP_MEMORY_SCOPE_AGENT);
                while (__hip_atomic_load(&cnt[t], __ATOMIC_RELAXED,
                                         __HIP_MEMORY_SCOPE_AGENT) < 256u)
                    __builtin_amdgcn_s_sleep(2);
            }
            __syncthreads();               // all producers arrived; h fresh
        }
        stageH(0, 0);
        stageH(1, 1);

        f32x4 acc[4][3] = {};    // [m-frag][gate]
        short hsnap[4][4];       // h[m-frag rows][this lane's j]

        // vmcnt ladder. t>0 (post-spin __syncthreads drained Wr0/Wr1):
        // at ic0 wait, outstanding = h0(2) h1(2) st2(5) = 9; retire h0 ->
        // vmcnt(7). t=0 (no drain): 15 outstanding, retire oldest 8
        // (Wr0 Wr1 h0) -> also vmcnt(7). ic1: retire h1 -> vmcnt(10) =
        // steady. ic14: sgxA issue, retire st14 -> vmcnt(10). ic15: sgxB,
        // retire st15 -> vmcnt(6). Epilogue: vmcnt(0) drains sGX.
#pragma unroll
        for (int ic = 0; ic < 16; ++ic) {
            if (ic < 14) {
                stage(ic + 2, (ic + 2) & 3);
            } else if (ic == 14) {
#pragma unroll
                for (int i = 0; i < 5; ++i) sgx_load(wave * 5 + i);  // 40KB -> buf0
            } else {
                sgx_load(40 + wave);                  // 8KB -> buf1 head
            }
            if (ic == 0)       asm volatile("s_waitcnt vmcnt(7)"  : : : "memory");
            else if (ic < 15)  asm volatile("s_waitcnt vmcnt(10)" : : : "memory");
            else               asm volatile("s_waitcnt vmcnt(6)"  : : : "memory");
            __builtin_amdgcn_s_barrier();
            __builtin_amdgcn_sched_barrier(0);    // no reads hoist above publish

            short* buf = LDSF + (ic & 3) * 20480;

            if (ic == hchunk) {              // snapshot h[:, j0..j0+63]
#pragma unroll
                for (int mi = 0; mi < 4; ++mi)
#pragma unroll
                    for (int r = 0; r < 4; ++r) {
                        int mrow = wm + mi * 16 + fq * 4 + r;
                        hsnap[mi][r] = buf[mrow * 64 + (jj ^ ((mrow & 7) * 8))];
                    }
            }

#pragma unroll
            for (int kk = 0; kk < 2; ++kk) {
                bf16x8 af[4], bg[3];
                const int cbase = kk * 32 + fq * 8;
                const int csw = cbase ^ ((fm & 7) * 8);   // swizzled read col
#pragma unroll
                for (int mi = 0; mi < 4; ++mi)
                    af[mi] = *(const bf16x8*)(&buf[(wm + mi * 16 + fm) * 64 + csw]);
#pragma unroll
                for (int g = 0; g < 3; ++g)
                    bg[g] = *(const bf16x8*)(&buf[8192 + (jg * 48 + g * 16 + fm) * 64 + csw]);
                __builtin_amdgcn_s_setprio(1);
#pragma unroll
                for (int mi = 0; mi < 4; ++mi)
#pragma unroll
                    for (int g = 0; g < 3; ++g)
                        acc[mi][g] = __builtin_amdgcn_mfma_f32_16x16x32_bf16(af[mi], bg[g], acc[mi][g], 0, 0, 0);
                __builtin_amdgcn_s_setprio(0);
            }
        }

        // Drain sGX, publish within block, then epilogue: LDS/register-only
        // inputs; h goes out via device-scope (sc1) write-through stores.
        asm volatile("s_waitcnt vmcnt(0)" : : : "memory");
        __builtin_amdgcn_s_barrier();
        __builtin_amdgcn_sched_barrier(0);

        const short* sGX = LDSF;            // [0 .. 24576) shorts
#pragma unroll
        for (int mi = 0; mi < 4; ++mi) {
#pragma unroll
            for (int r = 0; r < 4; ++r) {
                int mloc = wm + mi * 16 + fq * 4 + r;
                int gm = m0 + mloc;
                int jsw = jj ^ ((mloc & 7) * 8);          // sGX swizzled col
                float xr = bf2f(sGX[        mloc * 64 + jsw]);
                float xi = bf2f(sGX[ 8192 + mloc * 64 + jsw]);
                float xn = bf2f(sGX[16384 + mloc * 64 + jsw]);

                float rg = 1.0f / (1.0f + __expf(-(xr + acc[mi][0][r] + bh_r)));
                float ig = 1.0f / (1.0f + __expf(-(xi + acc[mi][1][r] + bh_i)));
                float ng = tanhf(xn + rg * (acc[mi][2][r] + bh_n));

                float h  = bf2f(hsnap[mi][r]);
                float hy = ng + ig * (h - ng);
                size_t idx = (size_t)gm * HID + jlane;
                // h: device-scope write-through (visible at IF$ to all XCDs)
                unsigned hv = (unsigned)(unsigned short)f2bf(hy);
                asm volatile("global_store_short %0, %1, off sc1"
                             :: "v"(hout + idx), "v"(hv) : "memory");
                if (t == TSTEP - 1) out[idx] = hy;
            }
        }

        if (t < TSTEP - 1) {
            __syncthreads();    // vmcnt(0): sc1 h-stores acked; LDS reads done
        }
    }
}

// x [b][t][600] fp32 -> x_bf [t*B + b][608] bf16 zero-padded (transpose)
__global__ __launch_bounds__(256) void cvt_x(const float* __restrict__ X, short* __restrict__ Xb) {
    int rd = blockIdx.x;             // dst row = t*BATCH + b
    int tt = rd >> 11;               // /2048
    int b  = rd & (BATCH - 1);
    const float* s = X + ((size_t)b * TSTEP + tt) * IN_D;
    short* d = Xb + (size_t)rd * IN_DP;
    for (int c = threadIdx.x; c < IN_DP; c += 256)
        d[c] = (c < IN_D) ? f2bf(s[c]) : (short)0;
}

// W_ih [3072,600] fp32 -> [3072,608] bf16 zero-padded
__global__ __launch_bounds__(256) void cvt_wih(const float* __restrict__ W, short* __restrict__ Wb) {
    int r = blockIdx.x;
    for (int c = threadIdx.x; c < IN_DP; c += 256) {
        float v = (c < IN_D) ? W[(size_t)r * IN_D + c] : 0.f;
        Wb[(size_t)r * IN_DP + c] = f2bf(v);
    }
}

// W_hh -> Wr gate-block-interleaved bf16: Wr[jb*48+g*16+ji] = Whh[g*1024+jb*16+ji]
__global__ __launch_bounds__(256) void cvt_whh(const float* __restrict__ W, short* __restrict__ Wr) {
    int n  = blockIdx.x;             // dst row 0..3071
    int jb = n / 48;
    int rem = n - jb * 48;
    int g  = rem >> 4;
    int ji = rem & 15;
    const float* s = W + (size_t)(g * HID + jb * 16 + ji) * HID;
    short* d = Wr + (size_t)n * HID;
    for (int c = threadIdx.x; c < HID; c += 256) d[c] = f2bf(s[c]);
}

extern "C" void kernel_launch(void* const* d_in, const int* in_sizes, int n_in,
                              void* d_out, int out_size, void* d_ws, size_t ws_size,
                              hipStream_t stream) {
    const float* x    = (const float*)d_in[0];  // [B, T, IN_D]
    const float* W_ih = (const float*)d_in[1];  // [3H, IN_D]
    const float* b_ih = (const float*)d_in[2];
    const float* W_hh = (const float*)d_in[3];  // [3H, HID]
    const float* b_hh = (const float*)d_in[4];
    float* out = (float*)d_out;                 // [B, HID]

    char* p = (char*)d_ws;
    short* gx     = (short*)p;  p += (size_t)BT * G3 * 2;       // 251.7 MB, [t][b][3H]
    short* x_bf   = (short*)p;  p += (size_t)BT * IN_DP * 2;    //  49.8 MB, [t][b][608]
    short* hb0    = (short*)p;  p += (size_t)BATCH * HID * 2;   //   4.2 MB
    short* hb1    = (short*)p;  p += (size_t)BATCH * HID * 2;   //   4.2 MB
    short* Wih_bf = (short*)p;  p += (size_t)G3 * IN_DP * 2;    //   3.7 MB
    short* Whh_r  = (short*)p;  p += (size_t)G3 * HID * 2;      //   6.3 MB
    unsigned* bar = (unsigned*)p; p += 256;                     // cnt[t] barrier
    // total ~320 MB

    cvt_wih<<<G3, 256, 0, stream>>>(W_ih, Wih_bf);
    cvt_whh<<<G3, 256, 0, stream>>>(W_hh, Whh_r);
    cvt_x<<<BT, 256, 0, stream>>>(x, x_bf);
    hipMemsetAsync(hb0, 0, (size_t)BATCH * HID * 2, stream);
    hipMemsetAsync(bar, 0, 256, stream);

    // One big input projection over all timesteps (M = 40960, 1D swizzled)
    gemm_input<<<7680, 256, 0, stream>>>(x_bf, Wih_bf, b_ih, gx);

    // All 20 recurrent steps in one persistent kernel (1 block/CU x 256)
    gru_fused<<<256, 512, 0, stream>>>(hb0, hb1, Whh_r, gx, b_hh, out, bar);
}

// Round 8
// 795.093 us; speedup vs baseline: 3.2749x; 1.6334x over previous
//
#include <hip/hip_runtime.h>
#include <hip/hip_bf16.h>
#include <math.h>

#define HID   1024
#define IN_D  600
#define IN_DP 640      // 600 padded to 10 x BK=64 chunks
#define BATCH 2048
#define TSTEP 20
#define BT    (BATCH * TSTEP)   // 40960
#define G3    3072

typedef __attribute__((ext_vector_type(8))) short bf16x8;
typedef __attribute__((ext_vector_type(4))) float f32x4;

#define GLB(p) ((const __attribute__((address_space(1))) void*)(p))
#define LDS(p) ((__attribute__((address_space(3))) void*)(p))

__device__ __forceinline__ short f2bf(float f) {
    __hip_bfloat16 b = __float2bfloat16(f);
    return *(short*)&b;
}
__device__ __forceinline__ float bf2f(short s) {
    __hip_bfloat16 b = *(__hip_bfloat16*)&s;
    return __bfloat162float(b);
}

// ---------------------------------------------------------------------------
// Input projection v2: counted-vmcnt pipeline (structure proven in-session
// by v7's gru_step: issue -> vmcnt(N) -> s_barrier -> read, NB=4 x 40KB).
// Old gemm_input was the m97 2-phase drain: 28% MfmaUtil, 1.87e7 bank
// conflicts, 640 TF. Here: 128m x 192n (=3 gates x 64j) per block, BK=64,
// K=640 (zero-padded -> identical fp32 sums), 10 chunks, 512 thr, XOR-swz.
// W_ih pre-interleaved like Wr (cvt_wih_r) so sB rows jg*48+g*16+fm map to
// n = g*1024 + j0 + jg*16 + fm; epilogue adds b_ih, stores gx [m][g*1024+j]
// -- exactly the layout gru_step's sgx_load consumes.
// Grid 5120 = 8 xcd x 2 jsub x 320 mblk (XCD-swizzled, j-panel L2-resident).
// ---------------------------------------------------------------------------
__global__ __launch_bounds__(512) void gemm_input2(const short* __restrict__ X,
                                                   const short* __restrict__ Wih_r,
                                                   const float* __restrict__ b_ih,
                                                   short* __restrict__ gx) {
    __shared__ short LDSF[4 * 20480];   // buf b at b*20480: sA@0 (16K), sB@8192 (24K)

    const int id    = blockIdx.x;
    const int xcd   = id & 7;
    const int local = id >> 3;          // 0..639
    const int jsub  = local & 1;
    const int mblk  = local >> 1;       // 0..319
    const int j0 = (xcd * 2 + jsub) * 64;
    const int m0 = mblk * 128;

    const int tid  = threadIdx.x;
    const int wave = tid >> 6;          // 0..7
    const int lane = tid & 63;
    const int wm = (wave >> 2) * 64;    // m-group: 0 or 64
    const int jg = wave & 3;            // j-group: 16 j each
    const int fm = lane & 15;
    const int fq = lane >> 4;

    const int srow8 = lane >> 3;                // 0..7
    const int sxor  = ((lane & 7) ^ srow8) * 8; // inverse-swizzled col (shorts)

    const short* Wblk = Wih_r + (size_t)(j0 * 3) * IN_DP;   // 192 rows, K=640

    f32x4 acc[4][3] = {};    // [m-frag][gate]

    // 5 uniform global_load_lds per wave per chunk (2 sA + 3 sB)
    auto stage = [&](int kc, int bsel) {
        int k0 = kc * 64;
        short* base = LDSF + bsel * 20480;
#pragma unroll
        for (int i = 0; i < 2; ++i) {
            int row0 = wave * 16 + i * 8;
            const short* g = X + (size_t)(m0 + row0 + srow8) * IN_DP + k0 + sxor;
            __builtin_amdgcn_global_load_lds(GLB(g), LDS(base + row0 * 64), 16, 0, 0);
        }
#pragma unroll
        for (int i = 0; i < 3; ++i) {
            int row0 = wave * 24 + i * 8;
            const short* g = Wblk + (size_t)(row0 + srow8) * IN_DP + k0 + sxor;
            __builtin_amdgcn_global_load_lds(GLB(g), LDS(base + 8192 + row0 * 64), 16, 0, 0);
        }
    };

    stage(0, 0);
    stage(1, 1);

#pragma unroll
    for (int ic = 0; ic < 10; ++ic) {
        if (ic < 8) stage(ic + 2, (ic + 2) & 3);
        if (ic < 8)       asm volatile("s_waitcnt vmcnt(10)" : : : "memory");
        else if (ic == 8) asm volatile("s_waitcnt vmcnt(5)"  : : : "memory");
        else              asm volatile("s_waitcnt vmcnt(0)"  : : : "memory");
        __builtin_amdgcn_s_barrier();
        __builtin_amdgcn_sched_barrier(0);

        short* buf = LDSF + (ic & 3) * 20480;

#pragma unroll
        for (int kk = 0; kk < 2; ++kk) {
            bf16x8 af[4], bg[3];
            const int cbase = kk * 32 + fq * 8;
            const int csw = cbase ^ ((fm & 7) * 8);
#pragma unroll
            for (int mi = 0; mi < 4; ++mi)
                af[mi] = *(const bf16x8*)(&buf[(wm + mi * 16 + fm) * 64 + csw]);
#pragma unroll
            for (int g = 0; g < 3; ++g)
                bg[g] = *(const bf16x8*)(&buf[8192 + (jg * 48 + g * 16 + fm) * 64 + csw]);
            __builtin_amdgcn_s_setprio(1);
#pragma unroll
            for (int mi = 0; mi < 4; ++mi)
#pragma unroll
                for (int g = 0; g < 3; ++g)
                    acc[mi][g] = __builtin_amdgcn_mfma_f32_16x16x32_bf16(af[mi], bg[g], acc[mi][g], 0, 0, 0);
            __builtin_amdgcn_s_setprio(0);
        }
    }

    // Epilogue: gx[gm][g*1024 + j0 + jg*16 + fm] = bf16(acc + b_ih)
    const int jl = j0 + jg * 16 + fm;
#pragma unroll
    for (int g = 0; g < 3; ++g) {
        float bias = b_ih[g * HID + jl];
#pragma unroll
        for (int mi = 0; mi < 4; ++mi) {
#pragma unroll
            for (int r = 0; r < 4; ++r) {
                int gm = m0 + wm + mi * 16 + fq * 4 + r;
                gx[(size_t)gm * G3 + g * HID + jl] = f2bf(acc[mi][g][r] + bias);
            }
        }
    }
}

// ---------------------------------------------------------------------------
// Fused recurrent step v7 (VERBATIM from the 839 us round-4 build; the
// persistent-fusion arc v8-v10 measured NET-NEGATIVE: kernel-boundary sync
// is cheaper than in-kernel device-scope coherence + 256-block spin).
// Counted-vmcnt pipeline: issue -> vmcnt(N) -> s_barrier -> read, NB=4.
// ---------------------------------------------------------------------------
__global__ __launch_bounds__(512) void gru_step(const short* __restrict__ hb_in,
                                                const short* __restrict__ Wr,
                                                const short* __restrict__ gx,
                                                const float* __restrict__ b_hh,
                                                short* __restrict__ hb_out,
                                                float* __restrict__ out,
                                                int t, int last) {
    __shared__ short LDSF[4 * 20480];   // 160 KB: buf b at b*20480 (sA@0, sB@8192)
                                        // sGX tail-overlay at [0 .. 24576)

    const int id   = blockIdx.x;
    const int xcd  = id & 7;
    const int rest = id >> 3;           // 0..31
    const int jsub = rest & 1;
    const int mblk = rest >> 1;         // 0..15
    const int j0 = (xcd * 2 + jsub) * 64;
    const int m0 = mblk * 128;
    const int hchunk = j0 >> 6;         // k-chunk holding h[:, j0..j0+63]

    const int tid  = threadIdx.x;
    const int wave = tid >> 6;          // 0..7
    const int lane = tid & 63;
    const int wm = (wave >> 2) * 64;    // m-group: 0 or 64
    const int jg = wave & 3;            // j-group: 16 j each
    const int fm = lane & 15;
    const int fq = lane >> 4;

    const int srow8 = lane >> 3;               // 0..7 (row within 8-row group)
    const int sxor  = ((lane & 7) ^ srow8) * 8; // inverse-swizzled col (shorts)

    const short* Wblk = Wr + (size_t)(j0 * 3) * HID;   // 192 rows, K=1024
    const short* gxt  = gx + (size_t)t * BATCH * G3;

    f32x4 acc[4][3] = {};    // [m-frag][gate]
    short hsnap[4][4];       // h[m-frag rows][this lane's j]

    // 5 global_load_lds per wave per chunk — UNIFORM across waves (vmcnt is
    // per-wave; the counted schedule requires symmetric issue counts).
    auto stage = [&](int kc, int bsel) {
        int k0 = kc * 64;
        short* base = LDSF + bsel * 20480;
#pragma unroll
        for (int i = 0; i < 2; ++i) {   // sA: 16 instrs over 8 waves
            int row0 = wave * 16 + i * 8;
            const short* g = hb_in + (size_t)(m0 + row0 + srow8) * HID + k0 + sxor;
            __builtin_amdgcn_global_load_lds(GLB(g), LDS(base + row0 * 64), 16, 0, 0);
        }
#pragma unroll
        for (int i = 0; i < 3; ++i) {   // sB: 24 instrs over 8 waves
            int row0 = wave * 24 + i * 8;
            const short* g = Wblk + (size_t)(row0 + srow8) * HID + k0 + sxor;
            __builtin_amdgcn_global_load_lds(GLB(g), LDS(base + 8192 + row0 * 64), 16, 0, 0);
        }
    };
    // sGX instr q (0..47): gate q>>4, rows (q&15)*8..+7, 64 swizzled j cols,
    // dest = LDSF + q*512 (buf0 + buf1 head).
    auto sgx_load = [&](int q) {
        int g = q >> 4;
        int row0 = (q & 15) * 8;
        const short* src = gxt + (size_t)(m0 + row0 + srow8) * G3 + g * HID + j0 + sxor;
        __builtin_amdgcn_global_load_lds(GLB(src), LDS(LDSF + q * 512), 16, 0, 0);
    };

    const int jj = jg * 16 + fm;        // block-local j (0..63)

    stage(0, 0);
    stage(1, 1);

#pragma unroll
    for (int ic = 0; ic < 16; ++ic) {
        // ---- issue (writes a buffer whose readers finished >=2 barriers ago)
        if (ic < 14) {
            stage(ic + 2, (ic + 2) & 3);          // 5 loads/wave
        } else if (ic == 14) {
#pragma unroll
            for (int i = 0; i < 5; ++i) sgx_load(wave * 5 + i);   // 40KB -> buf0
        } else {
            sgx_load(40 + wave);                  // 8KB -> buf1 head, 1/wave
        }
        // ---- counted wait on OWN chunk-ic loads, THEN publish via barrier.
        if (ic < 15) asm volatile("s_waitcnt vmcnt(10)" : : : "memory");
        else         asm volatile("s_waitcnt vmcnt(6)"  : : : "memory");
        __builtin_amdgcn_s_barrier();
        __builtin_amdgcn_sched_barrier(0);        // no reads hoist above publish

        short* buf = LDSF + (ic & 3) * 20480;

        if (ic == hchunk) {              // snapshot h[:, j0..j0+63] from sA
#pragma unroll
            for (int mi = 0; mi < 4; ++mi)
#pragma unroll
                for (int r = 0; r < 4; ++r) {
                    int mrow = wm + mi * 16 + fq * 4 + r;
                    hsnap[mi][r] = buf[mrow * 64 + (jj ^ ((mrow & 7) * 8))];
                }
        }

#pragma unroll
        for (int kk = 0; kk < 2; ++kk) {
            bf16x8 af[4], bg[3];
            const int cbase = kk * 32 + fq * 8;
            const int csw = cbase ^ ((fm & 7) * 8);   // swizzled read col
#pragma unroll
            for (int mi = 0; mi < 4; ++mi)
                af[mi] = *(const bf16x8*)(&buf[(wm + mi * 16 + fm) * 64 + csw]);
#pragma unroll
            for (int g = 0; g < 3; ++g)
                bg[g] = *(const bf16x8*)(&buf[8192 + (jg * 48 + g * 16 + fm) * 64 + csw]);
            __builtin_amdgcn_s_setprio(1);
#pragma unroll
            for (int mi = 0; mi < 4; ++mi)
#pragma unroll
                for (int g = 0; g < 3; ++g)
                    acc[mi][g] = __builtin_amdgcn_mfma_f32_16x16x32_bf16(af[mi], bg[g], acc[mi][g], 0, 0, 0);
            __builtin_amdgcn_s_setprio(0);
        }
    }

    // Drain sGX (only remaining outstanding loads), publish, then the
    // epilogue is LDS/register-only inputs; global STORES only.
    asm volatile("s_waitcnt vmcnt(0)" : : : "memory");
    __builtin_amdgcn_s_barrier();
    __builtin_amdgcn_sched_barrier(0);

    const short* sGX = LDSF;            // [0 .. 24576) shorts
    const int jlane = j0 + jj;
    const float bh_r = b_hh[jlane];
    const float bh_i = b_hh[HID + jlane];
    const float bh_n = b_hh[2 * HID + jlane];

#pragma unroll
    for (int mi = 0; mi < 4; ++mi) {
#pragma unroll
        for (int r = 0; r < 4; ++r) {
            int mloc = wm + mi * 16 + fq * 4 + r;
            int gm = m0 + mloc;
            int jsw = jj ^ ((mloc & 7) * 8);          // sGX swizzled col
            float xr = bf2f(sGX[        mloc * 64 + jsw]);
            float xi = bf2f(sGX[ 8192 + mloc * 64 + jsw]);
            float xn = bf2f(sGX[16384 + mloc * 64 + jsw]);

            float rg = 1.0f / (1.0f + __expf(-(xr + acc[mi][0][r] + bh_r)));
            float ig = 1.0f / (1.0f + __expf(-(xi + acc[mi][1][r] + bh_i)));
            float ng = tanhf(xn + rg * (acc[mi][2][r] + bh_n));

            float h  = bf2f(hsnap[mi][r]);
            float hy = ng + ig * (h - ng);
            size_t idx = (size_t)gm * HID + jlane;
            hb_out[idx] = f2bf(hy);
            if (last) out[idx] = hy;
        }
    }
}

// x [b][t][600] fp32 -> x_bf [t*B + b][640] bf16 zero-padded (transpose)
__global__ __launch_bounds__(256) void cvt_x(const float* __restrict__ X, short* __restrict__ Xb) {
    int rd = blockIdx.x;             // dst row = t*BATCH + b
    int tt = rd >> 11;               // /2048
    int b  = rd & (BATCH - 1);
    const float* s = X + ((size_t)b * TSTEP + tt) * IN_D;
    short* d = Xb + (size_t)rd * IN_DP;
    for (int c = threadIdx.x; c < IN_DP; c += 256)
        d[c] = (c < IN_D) ? f2bf(s[c]) : (short)0;
}

// W_ih -> gate-block-interleaved bf16 [3072][640]:
// dst row jb*48+g*16+ji = W_ih[g*1024 + jb*16 + ji], zero-padded K 600->640
__global__ __launch_bounds__(256) void cvt_wih_r(const float* __restrict__ W, short* __restrict__ Wb) {
    int n  = blockIdx.x;             // dst row 0..3071
    int jb = n / 48;
    int rem = n - jb * 48;
    int g  = rem >> 4;
    int ji = rem & 15;
    const float* s = W + (size_t)(g * HID + jb * 16 + ji) * IN_D;
    short* d = Wb + (size_t)n * IN_DP;
    for (int c = threadIdx.x; c < IN_DP; c += 256)
        d[c] = (c < IN_D) ? f2bf(s[c]) : (short)0;
}

// W_hh -> Wr gate-block-interleaved bf16: Wr[jb*48+g*16+ji] = Whh[g*1024+jb*16+ji]
__global__ __launch_bounds__(256) void cvt_whh(const float* __restrict__ W, short* __restrict__ Wr) {
    int n  = blockIdx.x;             // dst row 0..3071
    int jb = n / 48;
    int rem = n - jb * 48;
    int g  = rem >> 4;
    int ji = rem & 15;
    const float* s = W + (size_t)(g * HID + jb * 16 + ji) * HID;
    short* d = Wr + (size_t)n * HID;
    for (int c = threadIdx.x; c < HID; c += 256) d[c] = f2bf(s[c]);
}

extern "C" void kernel_launch(void* const* d_in, const int* in_sizes, int n_in,
                              void* d_out, int out_size, void* d_ws, size_t ws_size,
                              hipStream_t stream) {
    const float* x    = (const float*)d_in[0];  // [B, T, IN_D]
    const float* W_ih = (const float*)d_in[1];  // [3H, IN_D]
    const float* b_ih = (const float*)d_in[2];
    const float* W_hh = (const float*)d_in[3];  // [3H, HID]
    const float* b_hh = (const float*)d_in[4];
    float* out = (float*)d_out;                 // [B, HID]

    char* p = (char*)d_ws;
    short* gx     = (short*)p;  p += (size_t)BT * G3 * 2;       // 251.7 MB, [t][b][3H]
    short* x_bf   = (short*)p;  p += (size_t)BT * IN_DP * 2;    //  52.4 MB, [t][b][640]
    short* hb0    = (short*)p;  p += (size_t)BATCH * HID * 2;   //   4.2 MB
    short* hb1    = (short*)p;  p += (size_t)BATCH * HID * 2;   //   4.2 MB
    short* Wih_r  = (short*)p;  p += (size_t)G3 * IN_DP * 2;    //   3.9 MB
    short* Whh_r  = (short*)p;  p += (size_t)G3 * HID * 2;      //   6.3 MB
    // total ~323 MB

    cvt_wih_r<<<G3, 256, 0, stream>>>(W_ih, Wih_r);
    cvt_whh<<<G3, 256, 0, stream>>>(W_hh, Whh_r);
    cvt_x<<<BT, 256, 0, stream>>>(x, x_bf);
    hipMemsetAsync(hb0, 0, (size_t)BATCH * HID * 2, stream);

    // Input projection, counted-vmcnt pipeline (5120 blocks x 512 threads)
    gemm_input2<<<5120, 512, 0, stream>>>(x_bf, Wih_r, b_ih, gx);

    // 20 fused recurrent steps (256 blocks x 512 threads, XCD-swizzled)
    for (int t = 0; t < TSTEP; ++t) {
        const short* hin = (t & 1) ? hb1 : hb0;
        short* hout      = (t & 1) ? hb0 : hb1;
        gru_step<<<256, 512, 0, stream>>>(hin, Whh_r, gx, b_hh,
                                          hout, out, t, t == TSTEP - 1 ? 1 : 0);
    }
}